// Round 8
// baseline (268.245 us; speedup 1.0000x reference)
//
#include <hip/hip_runtime.h>
#include <hip/hip_bf16.h>

#define NN    1024
#define DD    128
#define TILE  128
#define PITCH 136   // bf16 elems per LDS tile row: 128 + 8 pad
#define SQP   132   // f32 elems per LDS sq row: 128 + 4 pad
#define NBLK  1024

typedef __bf16 bf16_t;
typedef bf16_t bf16x8 __attribute__((ext_vector_type(8)));
typedef float  f32x4  __attribute__((ext_vector_type(4)));
typedef _Float16 half4 __attribute__((ext_vector_type(4)));

// ws layout: floats [0..67] as before; [68..255] pad; byte offset 1024: f16 sq
// buffer 16*1024*1024*2 = 33554432 B.
// [0] coord_sum [1] reg_sum [2] count_loss_sum [3] bce_sum
// [4+b] pos_sum [20+b] pos_cnt [36+b] neg_sum [52+b] neg_cnt

__global__ __launch_bounds__(256) void small_losses(
    const float* __restrict__ pcoord, const float* __restrict__ pts,
    const float* __restrict__ masks,  const float* __restrict__ pcount,
    float* __restrict__ ws) {
  __shared__ float sh[4][2];
  float coord = 0.f, cnt = 0.f;
  const int gt = blockIdx.x * 256 + threadIdx.x;
  const int stride = 16 * 256;

  const float4* a4 = (const float4*)pcoord;
  const float4* b4 = (const float4*)pts;
  for (int i = gt; i < 8192; i += stride) {
    float4 a = a4[i], b = b4[i];
    float dx = a.x-b.x, dy = a.y-b.y, dz = a.z-b.z, dw = a.w-b.w;
    coord += dx*dx + dy*dy + dz*dz + dw*dw;
  }
  const float* m = masks + blockIdx.x * NN;
  for (int i = threadIdx.x; i < NN; i += 256) cnt += m[i];

  const int lane = threadIdx.x & 63, w = threadIdx.x >> 6;
  #pragma unroll
  for (int o = 32; o; o >>= 1) {
    coord += __shfl_xor(coord, o);
    cnt   += __shfl_xor(cnt, o);
  }
  if (lane == 0) { sh[w][0] = coord; sh[w][1] = cnt; }
  __syncthreads();
  if (threadIdx.x == 0) {
    float c = 0.f, n = 0.f;
    for (int i = 0; i < 4; ++i) { c += sh[i][0]; n += sh[i][1]; }
    atomicAdd(&ws[0], c);
    float d = fabsf(pcount[blockIdx.x] - n);
    float term = (d < 1.f) ? 0.5f * d * d : d - 0.5f;
    atomicAdd(&ws[2], term);
  }
}

__device__ __forceinline__ void loss_elem(float l, float a, float s, int grow, int gcol,
    float& bsum, float& poss, float& posc, float& negs, float& negc) {
  bsum += fmaxf(l, 0.f) - l * a + __logf(1.f + __expf(-fabsf(l)));
  if (a > 0.5f) {
    poss += s; posc += 1.f;
  } else if (grow != gcol) {
    negc += 1.f;
    if (s < 1.f) {
      float d = sqrtf(fmaxf(s, 1e-12f));
      float h = 1.f - d;
      negs += h * h;
    }
  }
}

// ---------------- split path kernel A: gram -> sq (f16) to global ----------------
__global__ __launch_bounds__(512, 4) void gram_sq(
    const float* __restrict__ feat, _Float16* __restrict__ sqout,
    float* __restrict__ ws) {
  __shared__ __align__(16) char smem[2 * TILE * PITCH * sizeof(bf16_t)];
  bf16_t* lsA = (bf16_t*)smem;
  bf16_t* lsB = (bf16_t*)(smem + TILE * PITCH * sizeof(bf16_t));
  float*  sqb = (float*)smem;       // f32 overlay post-MFMA (128*132*4)
  __shared__ float nrmA[TILE], nrmB[TILE];
  __shared__ float red[8];

  const int bx  = blockIdx.x;
  const int b   = bx >> 6;
  const int tid = bx & 63;
  const int ti  = (tid >> 3) << 7;
  const int tj  = (tid & 7)  << 7;
  const bool diag = ((tid >> 3) == (tid & 7));

  const int t = threadIdx.x;
  const float* fb = feat + (size_t)b * NN * DD;

  float regsum = 0.f;
  #pragma unroll
  for (int it = 0; it < 8; ++it) {
    int cid  = it * 512 + t;
    int tile = cid >> 11;
    int sub  = cid & 2047;
    int row  = sub >> 4;
    int c8   = sub & 15;
    const float* src = fb + (size_t)((tile ? tj : ti) + row) * DD + c8 * 8;
    float4 u = *(const float4*)src;
    float4 v = *(const float4*)(src + 4);
    if (diag && tile == 0)
      regsum += u.x*u.x + u.y*u.y + u.z*u.z + u.w*u.w
              + v.x*v.x + v.y*v.y + v.z*v.z + v.w*v.w;
    bf16_t* dst = (tile ? lsB : lsA) + row * PITCH + c8 * 8;
    dst[0] = (bf16_t)u.x; dst[1] = (bf16_t)u.y; dst[2] = (bf16_t)u.z; dst[3] = (bf16_t)u.w;
    dst[4] = (bf16_t)v.x; dst[5] = (bf16_t)v.y; dst[6] = (bf16_t)v.z; dst[7] = (bf16_t)v.w;
  }
  __syncthreads();

  {
    int row  = t >> 1;
    int half = t & 1;
    const bf16_t* src = (row < TILE ? lsA + row * PITCH : lsB + (row - TILE) * PITCH)
                        + half * 64;
    float s = 0.f;
    #pragma unroll
    for (int c = 0; c < 8; ++c) {
      bf16x8 ch = *(const bf16x8*)(src + c * 8);
      #pragma unroll
      for (int i = 0; i < 8; ++i) { float v = (float)ch[i]; s += v * v; }
    }
    s += __shfl_xor(s, 1);
    if (half == 0) { if (row < TILE) nrmA[row] = s; else nrmB[row - TILE] = s; }
  }

  const int lane = t & 63;
  const int wave = t >> 6;
  const int lrow = lane & 15;
  const int quad = lane >> 4;

  f32x4 acc[8];
  #pragma unroll
  for (int fc = 0; fc < 8; ++fc) acc[fc] = (f32x4){0.f, 0.f, 0.f, 0.f};

  #pragma unroll
  for (int k0 = 0; k0 < DD; k0 += 32) {
    const int kc = k0 + quad * 8;
    bf16x8 aF = *(const bf16x8*)&lsA[(wave * 16 + lrow) * PITCH + kc];
    bf16x8 bF[8];
    #pragma unroll
    for (int fc = 0; fc < 8; ++fc)
      bF[fc] = *(const bf16x8*)&lsB[(fc * 16 + lrow) * PITCH + kc];
    #pragma unroll
    for (int fc = 0; fc < 8; ++fc)
      acc[fc] = __builtin_amdgcn_mfma_f32_16x16x32_bf16(aF, bF[fc], acc[fc], 0, 0, 0);
  }
  __syncthreads();

  {
    const int rbase = wave * 16 + quad * 4;
    #pragma unroll
    for (int fc = 0; fc < 8; ++fc) {
      const int ctile = fc * 16 + lrow;
      const float ncol = nrmB[ctile];
      #pragma unroll
      for (int r = 0; r < 4; ++r) {
        const int rtile = rbase + r;
        sqb[rtile * SQP + ctile] = fmaxf(nrmA[rtile] + ncol - 2.f * acc[fc][r], 0.f);
      }
    }
  }
  __syncthreads();

  // coalesced f16 write-out of the 128x128 sq tile
  {
    const int c4 = t & 31, r0 = t >> 5;
    _Float16* sb = sqout + (size_t)b * NN * NN + (size_t)(ti + r0) * NN + tj + c4 * 4;
    #pragma unroll
    for (int it = 0; it < 8; ++it) {
      float4 s = *(const float4*)&sqb[(it * 16 + r0) * SQP + c4 * 4];
      half4 h = { (_Float16)s.x, (_Float16)s.y, (_Float16)s.z, (_Float16)s.w };
      *(half4*)(sb + (size_t)it * 16 * NN) = h;
    }
  }

  if (diag) {
    #pragma unroll
    for (int o = 32; o; o >>= 1) regsum += __shfl_xor(regsum, o);
    if (lane == 0) red[wave] = regsum;
    __syncthreads();
    if (t == 0) {
      float s = 0.f;
      for (int w = 0; w < 8; ++w) s += red[w];
      atomicAdd(&ws[1], s);
    }
  }
}

// ---------------- split path kernel B: pure streaming BCE + contrastive ----------------
// grid = 16 batches x 64 blocks; block handles 16 full matrix rows; per iteration
// one row: 256 threads x float4. Depth-4 register pipeline, no LDS in hot loop.
__global__ __launch_bounds__(256, 6) void bce_stream(
    const float* __restrict__ logits, const float* __restrict__ adj,
    const _Float16* __restrict__ sq, float* __restrict__ ws) {
  __shared__ float red[4][5];
  const int b   = blockIdx.x >> 6;
  const int blk = blockIdx.x & 63;
  const int t   = threadIdx.x;
  const int row0 = blk * 16;
  const int gcol0 = t * 4;

  const size_t base = (size_t)b * NN * NN + (size_t)row0 * NN + gcol0;
  const float*    lp = logits + base;
  const float*    ap = adj + base;
  const _Float16* sp = sq + base;

  float4 Lb[4], Ab[4];
  half4  Sb[4];
  #pragma unroll
  for (int i = 0; i < 4; ++i) {
    Lb[i] = *(const float4*)(lp + (size_t)i * NN);
    Ab[i] = *(const float4*)(ap + (size_t)i * NN);
    Sb[i] = *(const half4*)(sp + (size_t)i * NN);
  }

  float bsum = 0.f, poss = 0.f, posc = 0.f, negs = 0.f, negc = 0.f;
  #pragma unroll
  for (int it = 0; it < 16; ++it) {
    float4 L = Lb[it & 3], A = Ab[it & 3];
    half4  S = Sb[it & 3];
    if (it < 12) {
      Lb[it & 3] = *(const float4*)(lp + (size_t)(it + 4) * NN);
      Ab[it & 3] = *(const float4*)(ap + (size_t)(it + 4) * NN);
      Sb[it & 3] = *(const half4*)(sp + (size_t)(it + 4) * NN);
    }
    const int grow = row0 + it;
    loss_elem(L.x, A.x, (float)S[0], grow, gcol0 + 0, bsum, poss, posc, negs, negc);
    loss_elem(L.y, A.y, (float)S[1], grow, gcol0 + 1, bsum, poss, posc, negs, negc);
    loss_elem(L.z, A.z, (float)S[2], grow, gcol0 + 2, bsum, poss, posc, negs, negc);
    loss_elem(L.w, A.w, (float)S[3], grow, gcol0 + 3, bsum, poss, posc, negs, negc);
  }

  const int lane = t & 63, wave = t >> 6;
  #pragma unroll
  for (int o = 32; o; o >>= 1) {
    bsum += __shfl_xor(bsum, o);
    poss += __shfl_xor(poss, o);
    posc += __shfl_xor(posc, o);
    negs += __shfl_xor(negs, o);
    negc += __shfl_xor(negc, o);
  }
  if (lane == 0) {
    red[wave][0] = bsum; red[wave][1] = poss; red[wave][2] = posc;
    red[wave][3] = negs; red[wave][4] = negc;
  }
  __syncthreads();
  if (t == 0) {
    float s0=0.f,s1=0.f,s2=0.f,s3=0.f,s4=0.f;
    for (int w = 0; w < 4; ++w) {
      s0 += red[w][0]; s1 += red[w][1]; s2 += red[w][2];
      s3 += red[w][3]; s4 += red[w][4];
    }
    atomicAdd(&ws[3], s0);
    atomicAdd(&ws[4 + b], s1);
    atomicAdd(&ws[20 + b], s2);
    atomicAdd(&ws[36 + b], s3);
    atomicAdd(&ws[52 + b], s4);
  }
}

// ---------------- fallback fused kernel (R7) if ws too small ----------------
__global__ __launch_bounds__(512, 4) void fused_gram_bce(
    const float* __restrict__ logits, const float* __restrict__ adj,
    const float* __restrict__ feat, float* __restrict__ ws) {
  __shared__ __align__(16) char smem[2 * TILE * PITCH * sizeof(bf16_t)];
  bf16_t* lsA = (bf16_t*)smem;
  bf16_t* lsB = (bf16_t*)(smem + TILE * PITCH * sizeof(bf16_t));
  float*  sqb = (float*)smem;
  __shared__ float nrmA[TILE], nrmB[TILE];
  __shared__ float red[8][6];

  const int bx  = blockIdx.x;
  const int b   = bx >> 6;
  const int tid = bx & 63;
  const int ti  = (tid >> 3) << 7;
  const int tj  = (tid & 7)  << 7;
  const bool diag = ((tid >> 3) == (tid & 7));

  const int t = threadIdx.x;
  const float* fb = feat + (size_t)b * NN * DD;

  float regsum = 0.f;
  #pragma unroll
  for (int it = 0; it < 8; ++it) {
    int cid  = it * 512 + t;
    int tile = cid >> 11;
    int sub  = cid & 2047;
    int row  = sub >> 4;
    int c8   = sub & 15;
    const float* src = fb + (size_t)((tile ? tj : ti) + row) * DD + c8 * 8;
    float4 u = *(const float4*)src;
    float4 v = *(const float4*)(src + 4);
    if (diag && tile == 0)
      regsum += u.x*u.x + u.y*u.y + u.z*u.z + u.w*u.w
              + v.x*v.x + v.y*v.y + v.z*v.z + v.w*v.w;
    bf16_t* dst = (tile ? lsB : lsA) + row * PITCH + c8 * 8;
    dst[0] = (bf16_t)u.x; dst[1] = (bf16_t)u.y; dst[2] = (bf16_t)u.z; dst[3] = (bf16_t)u.w;
    dst[4] = (bf16_t)v.x; dst[5] = (bf16_t)v.y; dst[6] = (bf16_t)v.z; dst[7] = (bf16_t)v.w;
  }
  __syncthreads();

  {
    int row  = t >> 1;
    int half = t & 1;
    const bf16_t* src = (row < TILE ? lsA + row * PITCH : lsB + (row - TILE) * PITCH)
                        + half * 64;
    float s = 0.f;
    #pragma unroll
    for (int c = 0; c < 8; ++c) {
      bf16x8 ch = *(const bf16x8*)(src + c * 8);
      #pragma unroll
      for (int i = 0; i < 8; ++i) { float v = (float)ch[i]; s += v * v; }
    }
    s += __shfl_xor(s, 1);
    if (half == 0) { if (row < TILE) nrmA[row] = s; else nrmB[row - TILE] = s; }
  }

  const int lane = t & 63;
  const int wave = t >> 6;
  const int lrow = lane & 15;
  const int quad = lane >> 4;

  f32x4 acc[8];
  #pragma unroll
  for (int fc = 0; fc < 8; ++fc) acc[fc] = (f32x4){0.f, 0.f, 0.f, 0.f};

  #pragma unroll
  for (int k0 = 0; k0 < DD; k0 += 32) {
    const int kc = k0 + quad * 8;
    bf16x8 aF = *(const bf16x8*)&lsA[(wave * 16 + lrow) * PITCH + kc];
    bf16x8 bF[8];
    #pragma unroll
    for (int fc = 0; fc < 8; ++fc)
      bF[fc] = *(const bf16x8*)&lsB[(fc * 16 + lrow) * PITCH + kc];
    #pragma unroll
    for (int fc = 0; fc < 8; ++fc)
      acc[fc] = __builtin_amdgcn_mfma_f32_16x16x32_bf16(aF, bF[fc], acc[fc], 0, 0, 0);
  }

  const int c4 = t & 31, r0 = t >> 5;
  const int gcol0 = tj + c4 * 4;
  const size_t base = (size_t)b * NN * NN;
  const float* lp = logits + base + (size_t)(ti + r0) * NN + gcol0;
  const float* ap = adj    + base + (size_t)(ti + r0) * NN + gcol0;
  float4 Lb[8], Ab[8];
  #pragma unroll
  for (int i = 0; i < 8; ++i) {
    Lb[i] = *(const float4*)(lp + (size_t)i * 16 * NN);
    Ab[i] = *(const float4*)(ap + (size_t)i * 16 * NN);
  }

  __syncthreads();

  {
    const int rbase = wave * 16 + quad * 4;
    #pragma unroll
    for (int fc = 0; fc < 8; ++fc) {
      const int ctile = fc * 16 + lrow;
      const float ncol = nrmB[ctile];
      #pragma unroll
      for (int r = 0; r < 4; ++r) {
        const int rtile = rbase + r;
        sqb[rtile * SQP + ctile] = fmaxf(nrmA[rtile] + ncol - 2.f * acc[fc][r], 0.f);
      }
    }
  }
  __syncthreads();

  float bsum = 0.f, poss = 0.f, posc = 0.f, negs = 0.f, negc = 0.f;
  #pragma unroll
  for (int it = 0; it < 8; ++it) {
    const int row  = it * 16 + r0;
    const int grow = ti + row;
    float4 L = Lb[it], A = Ab[it];
    float4 s = *(const float4*)&sqb[row * SQP + c4 * 4];
    loss_elem(L.x, A.x, s.x, grow, gcol0 + 0, bsum, poss, posc, negs, negc);
    loss_elem(L.y, A.y, s.y, grow, gcol0 + 1, bsum, poss, posc, negs, negc);
    loss_elem(L.z, A.z, s.z, grow, gcol0 + 2, bsum, poss, posc, negs, negc);
    loss_elem(L.w, A.w, s.w, grow, gcol0 + 3, bsum, poss, posc, negs, negc);
  }

  #pragma unroll
  for (int o = 32; o; o >>= 1) {
    bsum   += __shfl_xor(bsum, o);
    poss   += __shfl_xor(poss, o);
    posc   += __shfl_xor(posc, o);
    negs   += __shfl_xor(negs, o);
    negc   += __shfl_xor(negc, o);
    regsum += __shfl_xor(regsum, o);
  }
  if (lane == 0) {
    red[wave][0] = bsum; red[wave][1] = poss; red[wave][2] = posc;
    red[wave][3] = negs; red[wave][4] = negc; red[wave][5] = regsum;
  }
  __syncthreads();
  if (t == 0) {
    float s0=0.f,s1=0.f,s2=0.f,s3=0.f,s4=0.f,s5=0.f;
    for (int w = 0; w < 8; ++w) {
      s0 += red[w][0]; s1 += red[w][1]; s2 += red[w][2];
      s3 += red[w][3]; s4 += red[w][4]; s5 += red[w][5];
    }
    atomicAdd(&ws[3], s0);
    atomicAdd(&ws[4 + b], s1);
    atomicAdd(&ws[20 + b], s2);
    atomicAdd(&ws[36 + b], s3);
    atomicAdd(&ws[52 + b], s4);
    if (diag) atomicAdd(&ws[1], s5);
  }
}

__global__ void finalize(const float* __restrict__ ws, float* __restrict__ out) {
  if (threadIdx.x != 0 || blockIdx.x != 0) return;
  float coord = ws[0] / 32768.f;
  float reg   = ws[1] / 2097152.f;
  float cntl  = ws[2] / 16.f;
  float edge  = ws[3] / 16777216.f;
  float contra = 0.f;
  for (int b = 0; b < 16; ++b) {
    float p = ws[4 + b]  / fmaxf(ws[20 + b], 1.f);
    float n = ws[36 + b] / fmaxf(ws[52 + b], 1.f);
    contra += p + n;
  }
  contra *= (1.f / 16.f);
  float total = coord + 2.f * edge + 0.1f * cntl + 0.001f * reg + 0.1f * contra;
  out[0] = total; out[1] = coord; out[2] = edge;
  out[3] = cntl;  out[4] = reg;   out[5] = contra;
}

extern "C" void kernel_launch(void* const* d_in, const int* in_sizes, int n_in,
                              void* d_out, int out_size, void* d_ws, size_t ws_size,
                              hipStream_t stream) {
  (void)in_sizes; (void)n_in; (void)out_size;
  const float* pcoord = (const float*)d_in[0];
  const float* pts    = (const float*)d_in[1];
  const float* logits = (const float*)d_in[2];
  const float* adj    = (const float*)d_in[3];
  const float* masks  = (const float*)d_in[4];
  const float* pcount = (const float*)d_in[5];
  const float* nf     = (const float*)d_in[6];
  float* ws  = (float*)d_ws;
  float* out = (float*)d_out;

  const size_t need = 1024 + (size_t)16 * NN * NN * 2;  // header + f16 sq buffer
  hipMemsetAsync(ws, 0, 68 * sizeof(float), stream);
  small_losses<<<16, 256, 0, stream>>>(pcoord, pts, masks, pcount, ws);
  if (ws_size >= need) {
    _Float16* sqbuf = (_Float16*)((char*)d_ws + 1024);
    gram_sq<<<NBLK, 512, 0, stream>>>(nf, sqbuf, ws);
    bce_stream<<<1024, 256, 0, stream>>>(logits, adj, sqbuf, ws);
  } else {
    fused_gram_bce<<<NBLK, 512, 0, stream>>>(logits, adj, nf, ws);
  }
  finalize<<<1, 64, 0, stream>>>(ws, out);
}

// Round 9
// 226.579 us; speedup vs baseline: 1.1839x; 1.1839x over previous
//
#include <hip/hip_runtime.h>
#include <hip/hip_bf16.h>

#define NN    1024
#define DD    128
#define TILE  128
#define PITCH 136   // bf16 elems per LDS tile row: 128 + 8 pad
#define SQP   132   // f32 elems per LDS sq row: 128 + 4 pad
#define NBLK  1024

typedef __bf16 bf16_t;
typedef bf16_t bf16x8 __attribute__((ext_vector_type(8)));
typedef float  f32x4  __attribute__((ext_vector_type(4)));
typedef _Float16 half4 __attribute__((ext_vector_type(4)));

// ws layout: floats [0..67]; byte offset 1024: f16 sq buffer 16*1024*1024*2 B.
// [0] coord_sum [1] reg_sum [2] count_loss_sum [3] bce_sum
// [4+b] pos_sum [20+b] pos_cnt [36+b] neg_sum   (neg_cnt derived in finalize)

__global__ __launch_bounds__(256) void small_losses(
    const float* __restrict__ pcoord, const float* __restrict__ pts,
    const float* __restrict__ masks,  const float* __restrict__ pcount,
    float* __restrict__ ws) {
  __shared__ float sh[4][2];
  float coord = 0.f, cnt = 0.f;
  const int gt = blockIdx.x * 256 + threadIdx.x;
  const int stride = 16 * 256;

  const float4* a4 = (const float4*)pcoord;
  const float4* b4 = (const float4*)pts;
  for (int i = gt; i < 8192; i += stride) {
    float4 a = a4[i], b = b4[i];
    float dx = a.x-b.x, dy = a.y-b.y, dz = a.z-b.z, dw = a.w-b.w;
    coord += dx*dx + dy*dy + dz*dz + dw*dw;
  }
  const float* m = masks + blockIdx.x * NN;
  for (int i = threadIdx.x; i < NN; i += 256) cnt += m[i];

  const int lane = threadIdx.x & 63, w = threadIdx.x >> 6;
  #pragma unroll
  for (int o = 32; o; o >>= 1) {
    coord += __shfl_xor(coord, o);
    cnt   += __shfl_xor(cnt, o);
  }
  if (lane == 0) { sh[w][0] = coord; sh[w][1] = cnt; }
  __syncthreads();
  if (threadIdx.x == 0) {
    float c = 0.f, n = 0.f;
    for (int i = 0; i < 4; ++i) { c += sh[i][0]; n += sh[i][1]; }
    atomicAdd(&ws[0], c);
    float d = fabsf(pcount[blockIdx.x] - n);
    float term = (d < 1.f) ? 0.5f * d * d : d - 0.5f;
    atomicAdd(&ws[2], term);
  }
}

__device__ __forceinline__ void loss_elem(float l, float a, float s, bool offd,
    float& bsum, float& poss, float& posc, float& negs) {
  bsum += fmaxf(l, 0.f) - l * a + __logf(1.f + __expf(-fabsf(l)));
  const bool pos = a > 0.5f;
  poss += pos ? s : 0.f;
  posc += pos ? 1.f : 0.f;
  if (!pos && offd && s < 1.f) {        // ~never taken -> execz-skipped
    float d = sqrtf(fmaxf(s, 1e-12f));
    float h = 1.f - d;
    negs += h * h;
  }
}

// ---------------- kernel A: gram -> sq (f16) to global ----------------
__global__ __launch_bounds__(512, 4) void gram_sq(
    const float* __restrict__ feat, _Float16* __restrict__ sqout,
    float* __restrict__ ws) {
  __shared__ __align__(16) char smem[2 * TILE * PITCH * sizeof(bf16_t)];
  bf16_t* lsA = (bf16_t*)smem;
  bf16_t* lsB = (bf16_t*)(smem + TILE * PITCH * sizeof(bf16_t));
  float*  sqb = (float*)smem;       // f32 overlay post-MFMA (128*132*4)
  __shared__ float nrmA[TILE], nrmB[TILE];
  __shared__ float red[8];

  const int bx  = blockIdx.x;
  const int b   = bx >> 6;
  const int tid = bx & 63;
  const int ti  = (tid >> 3) << 7;
  const int tj  = (tid & 7)  << 7;
  const bool diag = ((tid >> 3) == (tid & 7));

  const int t = threadIdx.x;
  const float* fb = feat + (size_t)b * NN * DD;

  float regsum = 0.f;
  #pragma unroll
  for (int it = 0; it < 8; ++it) {
    int cid  = it * 512 + t;
    int tile = cid >> 11;
    int sub  = cid & 2047;
    int row  = sub >> 4;
    int c8   = sub & 15;
    const float* src = fb + (size_t)((tile ? tj : ti) + row) * DD + c8 * 8;
    float4 u = *(const float4*)src;
    float4 v = *(const float4*)(src + 4);
    if (diag && tile == 0)
      regsum += u.x*u.x + u.y*u.y + u.z*u.z + u.w*u.w
              + v.x*v.x + v.y*v.y + v.z*v.z + v.w*v.w;
    bf16_t* dst = (tile ? lsB : lsA) + row * PITCH + c8 * 8;
    dst[0] = (bf16_t)u.x; dst[1] = (bf16_t)u.y; dst[2] = (bf16_t)u.z; dst[3] = (bf16_t)u.w;
    dst[4] = (bf16_t)v.x; dst[5] = (bf16_t)v.y; dst[6] = (bf16_t)v.z; dst[7] = (bf16_t)v.w;
  }
  __syncthreads();

  {
    int row  = t >> 1;
    int half = t & 1;
    const bf16_t* src = (row < TILE ? lsA + row * PITCH : lsB + (row - TILE) * PITCH)
                        + half * 64;
    float s = 0.f;
    #pragma unroll
    for (int c = 0; c < 8; ++c) {
      bf16x8 ch = *(const bf16x8*)(src + c * 8);
      #pragma unroll
      for (int i = 0; i < 8; ++i) { float v = (float)ch[i]; s += v * v; }
    }
    s += __shfl_xor(s, 1);
    if (half == 0) { if (row < TILE) nrmA[row] = s; else nrmB[row - TILE] = s; }
  }

  const int lane = t & 63;
  const int wave = t >> 6;
  const int lrow = lane & 15;
  const int quad = lane >> 4;

  f32x4 acc[8];
  #pragma unroll
  for (int fc = 0; fc < 8; ++fc) acc[fc] = (f32x4){0.f, 0.f, 0.f, 0.f};

  #pragma unroll
  for (int k0 = 0; k0 < DD; k0 += 32) {
    const int kc = k0 + quad * 8;
    bf16x8 aF = *(const bf16x8*)&lsA[(wave * 16 + lrow) * PITCH + kc];
    bf16x8 bF[8];
    #pragma unroll
    for (int fc = 0; fc < 8; ++fc)
      bF[fc] = *(const bf16x8*)&lsB[(fc * 16 + lrow) * PITCH + kc];
    #pragma unroll
    for (int fc = 0; fc < 8; ++fc)
      acc[fc] = __builtin_amdgcn_mfma_f32_16x16x32_bf16(aF, bF[fc], acc[fc], 0, 0, 0);
  }
  __syncthreads();

  {
    const int rbase = wave * 16 + quad * 4;
    #pragma unroll
    for (int fc = 0; fc < 8; ++fc) {
      const int ctile = fc * 16 + lrow;
      const float ncol = nrmB[ctile];
      #pragma unroll
      for (int r = 0; r < 4; ++r) {
        const int rtile = rbase + r;
        sqb[rtile * SQP + ctile] = fmaxf(nrmA[rtile] + ncol - 2.f * acc[fc][r], 0.f);
      }
    }
  }
  __syncthreads();

  // coalesced f16 write-out of the 128x128 sq tile
  {
    const int c4 = t & 31, r0 = t >> 5;
    _Float16* sb = sqout + (size_t)b * NN * NN + (size_t)(ti + r0) * NN + tj + c4 * 4;
    for (int it = 0; it < 8; ++it) {
      float4 s = *(const float4*)&sqb[(it * 16 + r0) * SQP + c4 * 4];
      half4 h = { (_Float16)s.x, (_Float16)s.y, (_Float16)s.z, (_Float16)s.w };
      *(half4*)(sb + (size_t)it * 16 * NN) = h;
    }
  }

  if (diag) {
    #pragma unroll
    for (int o = 32; o; o >>= 1) regsum += __shfl_xor(regsum, o);
    if (lane == 0) red[wave] = regsum;
    __syncthreads();
    if (t == 0) {
      float s = 0.f;
      for (int w = 0; w < 8; ++w) s += red[w];
      atomicAdd(&ws[1], s);
    }
  }
}

// ---------------- kernel B: simple streaming BCE + contrastive ----------------
// 2048 blocks (16 batches x 128), 256 threads, 8 rows of the 1024x1024 matrix
// per block. Plain loop, no manual register pipeline (the allocator spills
// those -- R7/R8 evidence). TLP does the latency hiding.
__global__ __launch_bounds__(256) void bce_stream(
    const float* __restrict__ logits, const float* __restrict__ adj,
    const _Float16* __restrict__ sq, float* __restrict__ ws) {
  __shared__ float red[4][4];
  const int b   = blockIdx.x >> 7;
  const int blk = blockIdx.x & 127;
  const int t   = threadIdx.x;
  const int row0 = blk * 8;
  const size_t base = (size_t)b * NN * NN + (size_t)row0 * NN;
  const float4* lp = (const float4*)(logits + base);
  const float4* ap = (const float4*)(adj + base);
  const half4*  sp = (const half4*)(sq + base);

  float bsum = 0.f, poss = 0.f, posc = 0.f, negs = 0.f;
  #pragma unroll 2
  for (int i = t; i < 2048; i += 256) {
    float4 L = lp[i];
    float4 A = ap[i];
    half4  S = sp[i];
    const int grow  = row0 + (i >> 8);
    const int gcol0 = (i & 255) * 4;
    loss_elem(L.x, A.x, (float)S[0], grow != gcol0 + 0, bsum, poss, posc, negs);
    loss_elem(L.y, A.y, (float)S[1], grow != gcol0 + 1, bsum, poss, posc, negs);
    loss_elem(L.z, A.z, (float)S[2], grow != gcol0 + 2, bsum, poss, posc, negs);
    loss_elem(L.w, A.w, (float)S[3], grow != gcol0 + 3, bsum, poss, posc, negs);
  }

  const int lane = t & 63, wave = t >> 6;
  #pragma unroll
  for (int o = 32; o; o >>= 1) {
    bsum += __shfl_xor(bsum, o);
    poss += __shfl_xor(poss, o);
    posc += __shfl_xor(posc, o);
    negs += __shfl_xor(negs, o);
  }
  if (lane == 0) {
    red[wave][0] = bsum; red[wave][1] = poss;
    red[wave][2] = posc; red[wave][3] = negs;
  }
  __syncthreads();
  if (t == 0) {
    float s0=0.f,s1=0.f,s2=0.f,s3=0.f;
    for (int w = 0; w < 4; ++w) {
      s0 += red[w][0]; s1 += red[w][1]; s2 += red[w][2]; s3 += red[w][3];
    }
    atomicAdd(&ws[3], s0);
    atomicAdd(&ws[4 + b], s1);
    atomicAdd(&ws[20 + b], s2);
    atomicAdd(&ws[36 + b], s3);
  }
}

__global__ void finalize(const float* __restrict__ ws, float* __restrict__ out) {
  if (threadIdx.x != 0 || blockIdx.x != 0) return;
  float coord = ws[0] / 32768.f;
  float reg   = ws[1] / 2097152.f;
  float cntl  = ws[2] / 16.f;
  float edge  = ws[3] / 16777216.f;
  float contra = 0.f;
  for (int b = 0; b < 16; ++b) {
    float negcnt = 1048576.f - 1024.f - ws[20 + b];   // N^2 - N - pos_cnt
    float p = ws[4 + b]  / fmaxf(ws[20 + b], 1.f);
    float n = ws[36 + b] / fmaxf(negcnt, 1.f);
    contra += p + n;
  }
  contra *= (1.f / 16.f);
  float total = coord + 2.f * edge + 0.1f * cntl + 0.001f * reg + 0.1f * contra;
  out[0] = total; out[1] = coord; out[2] = edge;
  out[3] = cntl;  out[4] = reg;   out[5] = contra;
}

extern "C" void kernel_launch(void* const* d_in, const int* in_sizes, int n_in,
                              void* d_out, int out_size, void* d_ws, size_t ws_size,
                              hipStream_t stream) {
  (void)in_sizes; (void)n_in; (void)out_size;
  const float* pcoord = (const float*)d_in[0];
  const float* pts    = (const float*)d_in[1];
  const float* logits = (const float*)d_in[2];
  const float* adj    = (const float*)d_in[3];
  const float* masks  = (const float*)d_in[4];
  const float* pcount = (const float*)d_in[5];
  const float* nf     = (const float*)d_in[6];
  float* ws  = (float*)d_ws;
  float* out = (float*)d_out;

  hipMemsetAsync(ws, 0, 68 * sizeof(float), stream);
  small_losses<<<16, 256, 0, stream>>>(pcoord, pts, masks, pcount, ws);
  _Float16* sqbuf = (_Float16*)((char*)d_ws + 1024);
  gram_sq<<<NBLK, 512, 0, stream>>>(nf, sqbuf, ws);
  bce_stream<<<2048, 256, 0, stream>>>(logits, adj, sqbuf, ws);
  finalize<<<1, 64, 0, stream>>>(ws, out);
}